// Round 9
// baseline (372.820 us; speedup 1.0000x reference)
//
#include <hip/hip_runtime.h>

#define TH 512
#define BPB 8   // batch elements per block (one per 64-lane wave)

typedef float f32x2 __attribute__((ext_vector_type(2)));

__device__ __forceinline__ f32x2 mk2(float a, float b) { f32x2 r; r.x = a; r.y = b; return r; }
// packed fp32 FMA: d.lo=fma(a.lo,b.lo,c.lo), d.hi=fma(a.hi,b.hi,c.hi)
__device__ __forceinline__ f32x2 pkfma(f32x2 a, f32x2 b, f32x2 c) {
  asm("v_pk_fma_f32 %0, %1, %2, %3" : "=v"(c) : "v"(a), "v"(b), "0"(c));
  return c;
}
// broadcast b.lo / b.hi to both halves
__device__ __forceinline__ f32x2 pkfma_blo(f32x2 a, f32x2 b, f32x2 c) {
  asm("v_pk_fma_f32 %0, %1, %2, %3 op_sel_hi:[1,0,1]" : "=v"(c) : "v"(a), "v"(b), "0"(c));
  return c;
}
__device__ __forceinline__ f32x2 pkfma_bhi(f32x2 a, f32x2 b, f32x2 c) {
  asm("v_pk_fma_f32 %0, %1, %2, %3 op_sel:[0,1,0] op_sel_hi:[1,1,1]" : "=v"(c) : "v"(a), "v"(b), "0"(c));
  return c;
}

__device__ __forceinline__ float sigm(float x) {
  return __fdividef(1.0f, 1.0f + __expf(-x));
}
__device__ __forceinline__ float fast_tanh(float x) {
  float ex = __expf(2.0f * x);
  return 1.0f - __fdividef(2.0f, ex + 1.0f);
}
// exact-GELU via branchless Abramowitz-Stegun 7.1.26 erf (|err| <= 1.5e-7)
__device__ __forceinline__ float gelu_erf(float a) {
  float z = fabsf(a) * 0.70710678118654752440f;
  float t = __fdividef(1.0f, __builtin_fmaf(0.3275911f, z, 1.0f));
  float p = __builtin_fmaf(1.061405429f, t, -1.453152027f);
  p = __builtin_fmaf(p, t, 1.421413741f);
  p = __builtin_fmaf(p, t, -0.284496736f);
  p = __builtin_fmaf(p, t, 0.254829592f);
  p = p * t;
  float e = __expf(-z * z);
  float y = __builtin_fmaf(-p, e, 1.0f);          // erf(|a|/sqrt2)
  return 0.5f * a * (1.0f + copysignf(y, a));
}

// wave-local ordering fence: each wave's scratch is private
#define WAVE_SYNC() asm volatile("s_waitcnt lgkmcnt(0)" ::: "memory")

// dot of LDS row (16 floats, 16B-aligned) with reg vector x[8] (f32x2 pairs), + bias
__device__ __forceinline__ float dot16b(const float* __restrict__ p, const f32x2* x, float bias) {
  const float4 w0 = *(const float4*)(p);
  const float4 w1 = *(const float4*)(p + 4);
  const float4 w2 = *(const float4*)(p + 8);
  const float4 w3 = *(const float4*)(p + 12);
  f32x2 a = mk2(bias, 0.f), b = mk2(0.f, 0.f);
  a = pkfma(mk2(w0.x, w0.y), x[0], a); b = pkfma(mk2(w0.z, w0.w), x[1], b);
  a = pkfma(mk2(w1.x, w1.y), x[2], a); b = pkfma(mk2(w1.z, w1.w), x[3], b);
  a = pkfma(mk2(w2.x, w2.y), x[4], a); b = pkfma(mk2(w2.z, w2.w), x[5], b);
  a = pkfma(mk2(w3.x, w3.y), x[6], a); b = pkfma(mk2(w3.z, w3.w), x[7], b);
  f32x2 s = a + b;
  return s.x + s.y;
}

// ---------- prep: fold s2s.mix.dec -> M2T/C0, and wq into wk -> WKQ ----------
__global__ void prep_kernel(const float* __restrict__ s2s_w, const float* __restrict__ s2s_b,
                            const float* __restrict__ mix_w, const float* __restrict__ mix_b,
                            const float* __restrict__ dec_w, const float* __restrict__ dec_b,
                            const float* __restrict__ wq,    const float* __restrict__ wk,
                            float* __restrict__ M2T, float* __restrict__ C0,
                            float* __restrict__ WKQ) {
  const int pix = threadIdx.x;                 // 256 threads
  // WKQ[j][c] = sum_d wq[d][j] * wk[d][c]   (kq[n][j] = sum_c x[n][c]*WKQ[j][c])
  {
    const int j = pix >> 4, c = pix & 15;
    float a = 0.f;
    for (int d = 0; d < 16; ++d) a += wq[d*16 + j] * wk[d*16 + c];
    WKQ[pix] = a;
  }
  const int I = pix >> 4, J = pix & 15;
  const int i = I >> 2, dd = I & 3, j = J >> 2, ee = J & 3;
  const int p = i*4 + j, q = dd*4 + ee;        // p: inner 4x4 spatial, q: dec tap
  float DWrow[64];
  for (int kc = 0; kc < 64; ++kc) {
    float a = 0.f;
    for (int o = 0; o < 16; ++o) a += dec_w[o*16 + q] * mix_w[o*64 + kc];
    DWrow[kc] = a;
  }
  float c0 = dec_b[0];
  for (int o = 0; o < 16; ++o) c0 += dec_w[o*16 + q] * mix_b[o];
  for (int k = 0; k < 4; ++k)
    for (int c = 0; c < 16; ++c) c0 += DWrow[k*16 + c] * s2s_b[c*16 + p];
  C0[pix] = c0;
  for (int k = 0; k < 4; ++k)
    for (int d = 0; d < 16; ++d) {
      float a = 0.f;
      for (int c = 0; c < 16; ++c) a += DWrow[k*16 + c] * s2s_w[(c*16 + p)*16 + d];
      M2T[(k*16 + d)*256 + pix] = a;
    }
}

__launch_bounds__(TH, 8)
__global__ void microslot_kernel(
    const float* __restrict__ frames,
    const float* __restrict__ enc_w, const float* __restrict__ enc_b,
    const float* __restrict__ ln_w,  const float* __restrict__ ln_b,
    const float* __restrict__ slot_mu,
    const float* __restrict__ wv,
    const float* __restrict__ wih, const float* __restrict__ whh,
    const float* __restrict__ bih, const float* __restrict__ bhh,
    const float* __restrict__ g_M2T, const float* __restrict__ g_C0,
    const float* __restrict__ g_WKQ,
    float* __restrict__ out)
{
  __shared__ __align__(16) float W_enc[16*20];   // [c][p] at c*20+p
  __shared__ __align__(16) float W_kq[16*20];    // WKQ[j][c] at j*20+c
  __shared__ __align__(16) float W_v[16*20];
  __shared__ __align__(16) float W_ih[48*20];
  __shared__ __align__(16) float W_hh[48*20];
  __shared__ float B_enc[16], LNW[16], LNB[16], B_ih[48], B_hh[48], MU[64];
  __shared__ __align__(16) float C0L[256];
  __shared__ __align__(16) float svb[BPB*68];    // svec[batch-row][64], stride 68
  __shared__ __align__(16) float SCR[BPB][768];  // per-wave scratch

  const int tid = threadIdx.x;

  for (int idx = tid; idx < 256; idx += TH) W_enc[(idx>>4)*20 + (idx&15)] = enc_w[idx];
  for (int idx = tid; idx < 256; idx += TH) W_kq [(idx>>4)*20 + (idx&15)] = g_WKQ[idx];
  for (int idx = tid; idx < 256; idx += TH) W_v  [(idx>>4)*20 + (idx&15)] = wv[idx];
  for (int idx = tid; idx < 768; idx += TH) W_ih[(idx>>4)*20 + (idx&15)] = wih[idx];
  for (int idx = tid; idx < 768; idx += TH) W_hh[(idx>>4)*20 + (idx&15)] = whh[idx];
  for (int idx = tid; idx < 256; idx += TH) C0L[idx] = g_C0[idx];
  if (tid < 16) { B_enc[tid] = enc_b[tid]; LNW[tid] = ln_w[tid]; LNB[tid] = ln_b[tid]; }
  if (tid >= 64  && tid < 112) B_ih[tid-64]  = bih[tid-64];
  if (tid >= 128 && tid < 176) B_hh[tid-128] = bhh[tid-128];
  if (tid >= 448) MU[tid-448] = slot_mu[tid-448];
  __syncthreads();

  const int wid = tid >> 6, lane = tid & 63;
  const int ln = lane & 15, lg = lane >> 4;      // lane = lg*16 + ln
  float* S = SCR[wid];
  // scratch (floats): sb[64] tmp[64] xq[16*20] vvT[16*20]
  constexpr int o_sb = 0, o_tmp = 64, o_xq = 128, o_vv = 448;

  float s_reg = MU[lane];                        // slots[k=lg][d=ln]
  const int i0 = ln >> 2, j0 = ln & 3;
  const size_t fbase = (size_t)(blockIdx.x * BPB + wid) * (8*256);

  for (int st = 0; st < 6; ++st) {
    const int t = st + 1;
    // ---------- P2: conv(k4s4) + bias + exact GELU + LayerNorm -> xq[n][c] ----------
    f32x2 patch2[8];
    {
      const float* fp = frames + fbase + (size_t)t*256;
      #pragma unroll
      for (int a = 0; a < 4; ++a) {
        float4 pv = *(const float4*)(fp + (4*i0 + a)*16 + 4*j0);
        patch2[2*a]   = mk2(pv.x, pv.y);
        patch2[2*a+1] = mk2(pv.z, pv.w);
      }
    }
    float x4[4];
    #pragma unroll
    for (int cc = 0; cc < 4; ++cc) {
      int c = 4*lg + cc;
      float acc = dot16b(&W_enc[c*20], patch2, B_enc[c]);
      x4[cc] = gelu_erf(acc);
    }
    float s1 = x4[0]+x4[1]+x4[2]+x4[3];
    float s2 = x4[0]*x4[0]+x4[1]*x4[1]+x4[2]*x4[2]+x4[3]*x4[3];
    s1 += __shfl_xor(s1, 16); s1 += __shfl_xor(s1, 32);
    s2 += __shfl_xor(s2, 16); s2 += __shfl_xor(s2, 32);
    float mu  = s1 * 0.0625f;
    float var = s2 * 0.0625f - mu*mu;
    float rs  = rsqrtf(var + 1e-5f);
    #pragma unroll
    for (int cc = 0; cc < 4; ++cc) {
      int c = 4*lg + cc;
      x4[cc] = (x4[cc]-mu)*rs*LNW[c] + LNB[c];
    }
    *(float4*)&S[o_xq + ln*20 + 4*lg] = make_float4(x4[0],x4[1],x4[2],x4[3]);
    WAVE_SYNC();

    // ---------- P3: kq[n][j] = x[n].WKQ[j]; vvT[d][n] = x[n].wv[d] ----------
    {
      f32x2 xr2[8];
      #pragma unroll
      for (int qd = 0; qd < 4; ++qd) {
        float4 v = *(const float4*)&S[o_xq + ln*20 + 4*qd];
        xr2[2*qd]   = mk2(v.x, v.y);
        xr2[2*qd+1] = mk2(v.z, v.w);
      }
      WAVE_SYNC();                     // x reads drained before kq overwrites the rows
      float kq4[4];
      #pragma unroll
      for (int cc = 0; cc < 4; ++cc) {
        int dd = 4*lg + cc;
        kq4[cc] = dot16b(&W_kq[dd*20], xr2, 0.f);
        S[o_vv + dd*20 + ln] = dot16b(&W_v[dd*20], xr2, 0.f);
      }
      *(float4*)&S[o_xq + ln*20 + 4*lg] = make_float4(kq4[0],kq4[1],kq4[2],kq4[3]);
      // no sync here: first P4 sync drains these writes
    }

    // ---------- P4: 3 slot-attention + GRU iterations ----------
    for (int it = 0; it < 3; ++it) {
      S[o_sb + lane] = s_reg;
      WAVE_SYNC();                     // drains kq/vv writes too (it==0)
      f32x2 hr2[8];                    // s[k=lg][:], reused as GRU h-rows
      #pragma unroll
      for (int qd = 0; qd < 4; ++qd) {
        float4 v = *(const float4*)&S[o_sb + lg*16 + 4*qd];
        hr2[2*qd]   = mk2(v.x, v.y);
        hr2[2*qd+1] = mk2(v.z, v.w);
      }
      float l = 0.25f * dot16b(&S[o_xq + ln*20], hr2, 0.f);  // logits[k=lg][n=ln]
      // softmax over K=4 slots; |logits| small by construction -> skip max subtraction
      float e = __expf(l);
      float se = e + __shfl_xor(e, 16); se += __shfl_xor(se, 32);
      S[o_tmp + lane] = __fdividef(e, se);   // attn[k][n]
      WAVE_SYNC();
      // upd[k=lg][d=ln] = attn[k][:] . vvT[:][d]
      float u;
      {
        float4 a0 = *(const float4*)&S[o_tmp + lg*16];
        float4 a1 = *(const float4*)&S[o_tmp + lg*16 + 4];
        float4 a2 = *(const float4*)&S[o_tmp + lg*16 + 8];
        float4 a3 = *(const float4*)&S[o_tmp + lg*16 + 12];
        float4 v0 = *(const float4*)&S[o_vv + ln*20];
        float4 v1 = *(const float4*)&S[o_vv + ln*20 + 4];
        float4 v2 = *(const float4*)&S[o_vv + ln*20 + 8];
        float4 v3 = *(const float4*)&S[o_vv + ln*20 + 12];
        f32x2 pa = mk2(0.f,0.f), pb = mk2(0.f,0.f);
        pa = pkfma(mk2(a0.x,a0.y), mk2(v0.x,v0.y), pa);
        pb = pkfma(mk2(a0.z,a0.w), mk2(v0.z,v0.w), pb);
        pa = pkfma(mk2(a1.x,a1.y), mk2(v1.x,v1.y), pa);
        pb = pkfma(mk2(a1.z,a1.w), mk2(v1.z,v1.w), pb);
        pa = pkfma(mk2(a2.x,a2.y), mk2(v2.x,v2.y), pa);
        pb = pkfma(mk2(a2.z,a2.w), mk2(v2.z,v2.w), pb);
        pa = pkfma(mk2(a3.x,a3.y), mk2(v3.x,v3.y), pa);
        pb = pkfma(mk2(a3.z,a3.w), mk2(v3.z,v3.w), pb);
        f32x2 ps = pa + pb;
        u = ps.x + ps.y;
      }
      S[o_tmp + lane] = u;             // same-wave WAR on tmp: in-order LDS pipe
      WAVE_SYNC();
      f32x2 ur2[8];
      #pragma unroll
      for (int qd = 0; qd < 4; ++qd) {
        float4 v = *(const float4*)&S[o_tmp + lg*16 + 4*qd];
        ur2[2*qd]   = mk2(v.x, v.y);
        ur2[2*qd+1] = mk2(v.z, v.w);
      }
      // GRU cell: gi = u@wih.T+bih, gh = h@whh.T+bhh (h = hr2)
      f32x2 gir2 = mk2(B_ih[ln],    0.f), ghr2 = mk2(B_hh[ln],    0.f);
      f32x2 giz2 = mk2(B_ih[16+ln], 0.f), ghz2 = mk2(B_hh[16+ln], 0.f);
      f32x2 gin2 = mk2(B_ih[32+ln], 0.f), ghn2 = mk2(B_hh[32+ln], 0.f);
      #pragma unroll
      for (int qd = 0; qd < 4; ++qd) {
        float4 wr = *(const float4*)&W_ih[(   ln)*20 + 4*qd];
        float4 wz = *(const float4*)&W_ih[(16+ln)*20 + 4*qd];
        float4 wn = *(const float4*)&W_ih[(32+ln)*20 + 4*qd];
        float4 vr = *(const float4*)&W_hh[(   ln)*20 + 4*qd];
        float4 vz = *(const float4*)&W_hh[(16+ln)*20 + 4*qd];
        float4 vn = *(const float4*)&W_hh[(32+ln)*20 + 4*qd];
        gir2 = pkfma(mk2(wr.x,wr.y), ur2[2*qd], gir2); gir2 = pkfma(mk2(wr.z,wr.w), ur2[2*qd+1], gir2);
        giz2 = pkfma(mk2(wz.x,wz.y), ur2[2*qd], giz2); giz2 = pkfma(mk2(wz.z,wz.w), ur2[2*qd+1], giz2);
        gin2 = pkfma(mk2(wn.x,wn.y), ur2[2*qd], gin2); gin2 = pkfma(mk2(wn.z,wn.w), ur2[2*qd+1], gin2);
        ghr2 = pkfma(mk2(vr.x,vr.y), hr2[2*qd], ghr2); ghr2 = pkfma(mk2(vr.z,vr.w), hr2[2*qd+1], ghr2);
        ghz2 = pkfma(mk2(vz.x,vz.y), hr2[2*qd], ghz2); ghz2 = pkfma(mk2(vz.z,vz.w), hr2[2*qd+1], ghz2);
        ghn2 = pkfma(mk2(vn.x,vn.y), hr2[2*qd], ghn2); ghn2 = pkfma(mk2(vn.z,vn.w), hr2[2*qd+1], ghn2);
      }
      float rg = sigm((gir2.x+gir2.y) + (ghr2.x+ghr2.y));
      float zg = sigm((giz2.x+giz2.y) + (ghz2.x+ghz2.y));
      float nh = fast_tanh((gin2.x+gin2.y) + rg*(ghn2.x+ghn2.y));
      s_reg = (1.f - zg)*nh + zg*s_reg;
    }

    // ---------- P5: block-cooperative decode via folded M2T ----------
    svb[wid*68 + lane] = s_reg;
    __syncthreads();
    {
      const int u = lane & 7, r = lane >> 3;
      const int pix = (wid << 5) | (u << 2);     // wave owns a 32-px column slice
      const float* m2p = g_M2T + pix;
      float4 c0 = *(const float4*)&C0L[pix];
      f32x2 a01 = mk2(c0.x, c0.y), a23 = mk2(c0.z, c0.w);
      #pragma unroll 4
      for (int q4 = 0; q4 < 16; ++q4) {
        float4 sv = *(const float4*)&svb[r*68 + 4*q4];
        f32x2 svA = mk2(sv.x, sv.y), svB = mk2(sv.z, sv.w);
        float4 m0 = *(const float4*)(m2p + (4*q4+0)*256);
        float4 m1 = *(const float4*)(m2p + (4*q4+1)*256);
        float4 m2 = *(const float4*)(m2p + (4*q4+2)*256);
        float4 m3 = *(const float4*)(m2p + (4*q4+3)*256);
        a01 = pkfma_blo(mk2(m0.x,m0.y), svA, a01); a23 = pkfma_blo(mk2(m0.z,m0.w), svA, a23);
        a01 = pkfma_bhi(mk2(m1.x,m1.y), svA, a01); a23 = pkfma_bhi(mk2(m1.z,m1.w), svA, a23);
        a01 = pkfma_blo(mk2(m2.x,m2.y), svB, a01); a23 = pkfma_blo(mk2(m2.z,m2.w), svB, a23);
        a01 = pkfma_bhi(mk2(m3.x,m3.y), svB, a01); a23 = pkfma_bhi(mk2(m3.z,m3.w), svB, a23);
      }
      const size_t ob = (size_t)(blockIdx.x*BPB + r)*(6*256) + (size_t)st*256 + pix;
      *(float4*)(out + ob) = make_float4(sigm(a01.x), sigm(a01.y), sigm(a23.x), sigm(a23.y));
    }
    __syncthreads();
  }
}

extern "C" void kernel_launch(void* const* d_in, const int* in_sizes, int n_in,
                              void* d_out, int out_size, void* d_ws, size_t ws_size,
                              hipStream_t stream) {
  const float* frames  = (const float*)d_in[0];
  const float* enc_w   = (const float*)d_in[1];
  const float* enc_b   = (const float*)d_in[2];
  const float* ln_w    = (const float*)d_in[3];
  const float* ln_b    = (const float*)d_in[4];
  const float* slot_mu = (const float*)d_in[5];
  const float* wq      = (const float*)d_in[6];
  const float* wk      = (const float*)d_in[7];
  const float* wv      = (const float*)d_in[8];
  const float* wih     = (const float*)d_in[9];
  const float* whh     = (const float*)d_in[10];
  const float* bih     = (const float*)d_in[11];
  const float* bhh     = (const float*)d_in[12];
  const float* s2s_w   = (const float*)d_in[13];
  const float* s2s_b   = (const float*)d_in[14];
  const float* mix_w   = (const float*)d_in[15];
  const float* mix_b   = (const float*)d_in[16];
  const float* dec_w   = (const float*)d_in[17];
  const float* dec_b   = (const float*)d_in[18];
  float* out = (float*)d_out;

  float* g_M2T = (float*)d_ws;            // 64*256 floats
  float* g_C0  = g_M2T + 64*256;          // 256 floats
  float* g_WKQ = g_C0 + 256;              // 256 floats (68,608 B total in d_ws)

  hipLaunchKernelGGL(prep_kernel, dim3(1), dim3(256), 0, stream,
                     s2s_w, s2s_b, mix_w, mix_b, dec_w, dec_b, wq, wk,
                     g_M2T, g_C0, g_WKQ);

  const int B = 16384;
  hipLaunchKernelGGL(microslot_kernel, dim3(B / BPB), dim3(TH), 0, stream,
                     frames, enc_w, enc_b, ln_w, ln_b, slot_mu, wv,
                     wih, whh, bih, bhh, g_M2T, g_C0, g_WKQ, out);
}

// Round 10
// 336.933 us; speedup vs baseline: 1.1065x; 1.1065x over previous
//
#include <hip/hip_runtime.h>

#define TH 512
#define BPB 8   // batch elements per block (one per 64-lane wave)

typedef float f32x2 __attribute__((ext_vector_type(2)));

__device__ __forceinline__ f32x2 mk2(float a, float b) { f32x2 r; r.x = a; r.y = b; return r; }
// packed fp32 FMA: d.lo=fma(a.lo,b.lo,c.lo), d.hi=fma(a.hi,b.hi,c.hi)
__device__ __forceinline__ f32x2 pkfma(f32x2 a, f32x2 b, f32x2 c) {
  asm("v_pk_fma_f32 %0, %1, %2, %3" : "=v"(c) : "v"(a), "v"(b), "0"(c));
  return c;
}
// broadcast b.lo / b.hi to both halves
__device__ __forceinline__ f32x2 pkfma_blo(f32x2 a, f32x2 b, f32x2 c) {
  asm("v_pk_fma_f32 %0, %1, %2, %3 op_sel_hi:[1,0,1]" : "=v"(c) : "v"(a), "v"(b), "0"(c));
  return c;
}
__device__ __forceinline__ f32x2 pkfma_bhi(f32x2 a, f32x2 b, f32x2 c) {
  asm("v_pk_fma_f32 %0, %1, %2, %3 op_sel:[0,1,0] op_sel_hi:[1,1,1]" : "=v"(c) : "v"(a), "v"(b), "0"(c));
  return c;
}

__device__ __forceinline__ float sigm(float x) {
  return __fdividef(1.0f, 1.0f + __expf(-x));
}
__device__ __forceinline__ float fast_tanh(float x) {
  float ex = __expf(2.0f * x);
  return 1.0f - __fdividef(2.0f, ex + 1.0f);
}
// exact-GELU via branchless Abramowitz-Stegun 7.1.26 erf (|err| <= 1.5e-7)
__device__ __forceinline__ float gelu_erf(float a) {
  float z = fabsf(a) * 0.70710678118654752440f;
  float t = __fdividef(1.0f, __builtin_fmaf(0.3275911f, z, 1.0f));
  float p = __builtin_fmaf(1.061405429f, t, -1.453152027f);
  p = __builtin_fmaf(p, t, 1.421413741f);
  p = __builtin_fmaf(p, t, -0.284496736f);
  p = __builtin_fmaf(p, t, 0.254829592f);
  p = p * t;
  float e = __expf(-z * z);
  float y = __builtin_fmaf(-p, e, 1.0f);          // erf(|a|/sqrt2)
  return 0.5f * a * (1.0f + copysignf(y, a));
}

// wave-local ordering fence: each wave's scratch is private
#define WAVE_SYNC() asm volatile("s_waitcnt lgkmcnt(0)" ::: "memory")

// dot of LDS row (16 floats, 16B-aligned) with reg vector x[8] (f32x2 pairs), + bias
__device__ __forceinline__ float dot16b(const float* __restrict__ p, const f32x2* x, float bias) {
  const float4 w0 = *(const float4*)(p);
  const float4 w1 = *(const float4*)(p + 4);
  const float4 w2 = *(const float4*)(p + 8);
  const float4 w3 = *(const float4*)(p + 12);
  f32x2 a = mk2(bias, 0.f), b = mk2(0.f, 0.f);
  a = pkfma(mk2(w0.x, w0.y), x[0], a); b = pkfma(mk2(w0.z, w0.w), x[1], b);
  a = pkfma(mk2(w1.x, w1.y), x[2], a); b = pkfma(mk2(w1.z, w1.w), x[3], b);
  a = pkfma(mk2(w2.x, w2.y), x[4], a); b = pkfma(mk2(w2.z, w2.w), x[5], b);
  a = pkfma(mk2(w3.x, w3.y), x[6], a); b = pkfma(mk2(w3.z, w3.w), x[7], b);
  f32x2 s = a + b;
  return s.x + s.y;
}

// ---------- prep: fold s2s.mix.dec -> M2T/C0, and wq into wk -> WKQ ----------
__global__ void prep_kernel(const float* __restrict__ s2s_w, const float* __restrict__ s2s_b,
                            const float* __restrict__ mix_w, const float* __restrict__ mix_b,
                            const float* __restrict__ dec_w, const float* __restrict__ dec_b,
                            const float* __restrict__ wq,    const float* __restrict__ wk,
                            float* __restrict__ M2T, float* __restrict__ C0,
                            float* __restrict__ WKQ) {
  const int pix = threadIdx.x;                 // 256 threads
  // WKQ[j][c] = sum_d wq[d][j] * wk[d][c]   (kq[n][j] = sum_c x[n][c]*WKQ[j][c])
  {
    const int j = pix >> 4, c = pix & 15;
    float a = 0.f;
    for (int d = 0; d < 16; ++d) a += wq[d*16 + j] * wk[d*16 + c];
    WKQ[pix] = a;
  }
  const int I = pix >> 4, J = pix & 15;
  const int i = I >> 2, dd = I & 3, j = J >> 2, ee = J & 3;
  const int p = i*4 + j, q = dd*4 + ee;        // p: inner 4x4 spatial, q: dec tap
  float DWrow[64];
  for (int kc = 0; kc < 64; ++kc) {
    float a = 0.f;
    for (int o = 0; o < 16; ++o) a += dec_w[o*16 + q] * mix_w[o*64 + kc];
    DWrow[kc] = a;
  }
  float c0 = dec_b[0];
  for (int o = 0; o < 16; ++o) c0 += dec_w[o*16 + q] * mix_b[o];
  for (int k = 0; k < 4; ++k)
    for (int c = 0; c < 16; ++c) c0 += DWrow[k*16 + c] * s2s_b[c*16 + p];
  C0[pix] = c0;
  for (int k = 0; k < 4; ++k)
    for (int d = 0; d < 16; ++d) {
      float a = 0.f;
      for (int c = 0; c < 16; ++c) a += DWrow[k*16 + c] * s2s_w[(c*16 + p)*16 + d];
      M2T[(k*16 + d)*256 + pix] = a;
    }
}

__launch_bounds__(TH, 8)
__global__ void microslot_kernel(
    const float* __restrict__ frames,
    const float* __restrict__ enc_w, const float* __restrict__ enc_b,
    const float* __restrict__ ln_w,  const float* __restrict__ ln_b,
    const float* __restrict__ slot_mu,
    const float* __restrict__ wv,
    const float* __restrict__ wih, const float* __restrict__ whh,
    const float* __restrict__ bih, const float* __restrict__ bhh,
    const float* __restrict__ g_M2T, const float* __restrict__ g_C0,
    const float* __restrict__ g_WKQ,
    float* __restrict__ out)
{
  __shared__ __align__(16) float W_enc[16*20];   // [c][p] at c*20+p
  __shared__ __align__(16) float W_kq[16*20];    // WKQ[j][c] at j*20+c
  __shared__ __align__(16) float W_v[16*20];
  __shared__ __align__(16) float W_ih[48*20];
  __shared__ __align__(16) float W_hh[48*20];
  __shared__ float B_enc[16], LNW[16], LNB[16], B_ih[48], B_hh[48], MU[64];
  __shared__ __align__(16) float C0L[256];
  __shared__ __align__(16) float svb[BPB*68];    // svec[batch-row][64], stride 68
  __shared__ __align__(16) float SCR[BPB][768];  // per-wave scratch

  const int tid = threadIdx.x;

  for (int idx = tid; idx < 256; idx += TH) W_enc[(idx>>4)*20 + (idx&15)] = enc_w[idx];
  for (int idx = tid; idx < 256; idx += TH) W_kq [(idx>>4)*20 + (idx&15)] = g_WKQ[idx];
  for (int idx = tid; idx < 256; idx += TH) W_v  [(idx>>4)*20 + (idx&15)] = wv[idx];
  for (int idx = tid; idx < 768; idx += TH) W_ih[(idx>>4)*20 + (idx&15)] = wih[idx];
  for (int idx = tid; idx < 768; idx += TH) W_hh[(idx>>4)*20 + (idx&15)] = whh[idx];
  for (int idx = tid; idx < 256; idx += TH) C0L[idx] = g_C0[idx];
  if (tid < 16) { B_enc[tid] = enc_b[tid]; LNW[tid] = ln_w[tid]; LNB[tid] = ln_b[tid]; }
  if (tid >= 64  && tid < 112) B_ih[tid-64]  = bih[tid-64];
  if (tid >= 128 && tid < 176) B_hh[tid-128] = bhh[tid-128];
  if (tid >= 448) MU[tid-448] = slot_mu[tid-448];
  __syncthreads();

  const int wid = tid >> 6, lane = tid & 63;
  const int ln = lane & 15, lg = lane >> 4;      // lane = lg*16 + ln
  float* S = SCR[wid];
  // scratch (floats): sb[64] tmp[64] xq[16*20] vvT[16*20]
  constexpr int o_sb = 0, o_tmp = 64, o_xq = 128, o_vv = 448;

  float s_reg = MU[lane];                        // slots[k=lg][d=ln]
  const int i0 = ln >> 2, j0 = ln & 3;
  const size_t fbase = (size_t)(blockIdx.x * BPB + wid) * (8*256);

  for (int st = 0; st < 6; ++st) {
    const int t = st + 1;
    // ---------- P2: conv(k4s4) + bias + exact GELU + LayerNorm -> xq[n][c] ----------
    f32x2 patch2[8];
    {
      const float* fp = frames + fbase + (size_t)t*256;
      #pragma unroll
      for (int a = 0; a < 4; ++a) {
        float4 pv = *(const float4*)(fp + (4*i0 + a)*16 + 4*j0);
        patch2[2*a]   = mk2(pv.x, pv.y);
        patch2[2*a+1] = mk2(pv.z, pv.w);
      }
    }
    float x4[4];
    #pragma unroll
    for (int cc = 0; cc < 4; ++cc) {
      int c = 4*lg + cc;
      float acc = dot16b(&W_enc[c*20], patch2, B_enc[c]);
      x4[cc] = gelu_erf(acc);
    }
    float s1 = x4[0]+x4[1]+x4[2]+x4[3];
    float s2 = x4[0]*x4[0]+x4[1]*x4[1]+x4[2]*x4[2]+x4[3]*x4[3];
    s1 += __shfl_xor(s1, 16); s1 += __shfl_xor(s1, 32);
    s2 += __shfl_xor(s2, 16); s2 += __shfl_xor(s2, 32);
    float mu  = s1 * 0.0625f;
    float var = s2 * 0.0625f - mu*mu;
    float rs  = rsqrtf(var + 1e-5f);
    #pragma unroll
    for (int cc = 0; cc < 4; ++cc) {
      int c = 4*lg + cc;
      x4[cc] = (x4[cc]-mu)*rs*LNW[c] + LNB[c];
    }
    *(float4*)&S[o_xq + ln*20 + 4*lg] = make_float4(x4[0],x4[1],x4[2],x4[3]);
    WAVE_SYNC();

    // ---------- P3: kq[n][j] = x[n].WKQ[j]; vvT[d][n] = x[n].wv[d] ----------
    {
      f32x2 xr2[8];
      #pragma unroll
      for (int qd = 0; qd < 4; ++qd) {
        float4 v = *(const float4*)&S[o_xq + ln*20 + 4*qd];
        xr2[2*qd]   = mk2(v.x, v.y);
        xr2[2*qd+1] = mk2(v.z, v.w);
      }
      // NOTE: no fence here. The kq write below is a same-wave WAR on the xq
      // rows; DS ops from one wave execute in order, so all lanes' x reads
      // (issued above) complete before the write issues. (Same property the
      // o_tmp overwrite in P4 relies on.)
      float kq4[4];
      #pragma unroll
      for (int cc = 0; cc < 4; ++cc) {
        int dd = 4*lg + cc;
        kq4[cc] = dot16b(&W_kq[dd*20], xr2, 0.f);
        S[o_vv + dd*20 + ln] = dot16b(&W_v[dd*20], xr2, 0.f);
      }
      *(float4*)&S[o_xq + ln*20 + 4*lg] = make_float4(kq4[0],kq4[1],kq4[2],kq4[3]);
      // no sync here: first P4 sync drains these writes
    }

    // ---------- P4: 3 slot-attention + GRU iterations ----------
    for (int it = 0; it < 3; ++it) {
      S[o_sb + lane] = s_reg;
      WAVE_SYNC();                     // drains kq/vv writes too (it==0)
      f32x2 hr2[8];                    // s[k=lg][:], reused as GRU h-rows
      #pragma unroll
      for (int qd = 0; qd < 4; ++qd) {
        float4 v = *(const float4*)&S[o_sb + lg*16 + 4*qd];
        hr2[2*qd]   = mk2(v.x, v.y);
        hr2[2*qd+1] = mk2(v.z, v.w);
      }
      float l = 0.25f * dot16b(&S[o_xq + ln*20], hr2, 0.f);  // logits[k=lg][n=ln]
      // softmax over K=4 slots; |logits| small by construction -> skip max subtraction
      float e = __expf(l);
      float se = e + __shfl_xor(e, 16); se += __shfl_xor(se, 32);
      S[o_tmp + lane] = __fdividef(e, se);   // attn[k][n]
      WAVE_SYNC();
      // upd[k=lg][d=ln] = attn[k][:] . vvT[:][d]
      float u;
      {
        float4 a0 = *(const float4*)&S[o_tmp + lg*16];
        float4 a1 = *(const float4*)&S[o_tmp + lg*16 + 4];
        float4 a2 = *(const float4*)&S[o_tmp + lg*16 + 8];
        float4 a3 = *(const float4*)&S[o_tmp + lg*16 + 12];
        float4 v0 = *(const float4*)&S[o_vv + ln*20];
        float4 v1 = *(const float4*)&S[o_vv + ln*20 + 4];
        float4 v2 = *(const float4*)&S[o_vv + ln*20 + 8];
        float4 v3 = *(const float4*)&S[o_vv + ln*20 + 12];
        f32x2 pa = mk2(0.f,0.f), pb = mk2(0.f,0.f);
        pa = pkfma(mk2(a0.x,a0.y), mk2(v0.x,v0.y), pa);
        pb = pkfma(mk2(a0.z,a0.w), mk2(v0.z,v0.w), pb);
        pa = pkfma(mk2(a1.x,a1.y), mk2(v1.x,v1.y), pa);
        pb = pkfma(mk2(a1.z,a1.w), mk2(v1.z,v1.w), pb);
        pa = pkfma(mk2(a2.x,a2.y), mk2(v2.x,v2.y), pa);
        pb = pkfma(mk2(a2.z,a2.w), mk2(v2.z,v2.w), pb);
        pa = pkfma(mk2(a3.x,a3.y), mk2(v3.x,v3.y), pa);
        pb = pkfma(mk2(a3.z,a3.w), mk2(v3.z,v3.w), pb);
        f32x2 ps = pa + pb;
        u = ps.x + ps.y;
      }
      S[o_tmp + lane] = u;             // same-wave WAR on tmp: in-order LDS pipe
      WAVE_SYNC();
      f32x2 ur2[8];
      #pragma unroll
      for (int qd = 0; qd < 4; ++qd) {
        float4 v = *(const float4*)&S[o_tmp + lg*16 + 4*qd];
        ur2[2*qd]   = mk2(v.x, v.y);
        ur2[2*qd+1] = mk2(v.z, v.w);
      }
      // GRU cell: gi = u@wih.T+bih, gh = h@whh.T+bhh (h = hr2)
      f32x2 gir2 = mk2(B_ih[ln],    0.f), ghr2 = mk2(B_hh[ln],    0.f);
      f32x2 giz2 = mk2(B_ih[16+ln], 0.f), ghz2 = mk2(B_hh[16+ln], 0.f);
      f32x2 gin2 = mk2(B_ih[32+ln], 0.f), ghn2 = mk2(B_hh[32+ln], 0.f);
      #pragma unroll
      for (int qd = 0; qd < 4; ++qd) {
        float4 wr = *(const float4*)&W_ih[(   ln)*20 + 4*qd];
        float4 wz = *(const float4*)&W_ih[(16+ln)*20 + 4*qd];
        float4 wn = *(const float4*)&W_ih[(32+ln)*20 + 4*qd];
        float4 vr = *(const float4*)&W_hh[(   ln)*20 + 4*qd];
        float4 vz = *(const float4*)&W_hh[(16+ln)*20 + 4*qd];
        float4 vn = *(const float4*)&W_hh[(32+ln)*20 + 4*qd];
        gir2 = pkfma(mk2(wr.x,wr.y), ur2[2*qd], gir2); gir2 = pkfma(mk2(wr.z,wr.w), ur2[2*qd+1], gir2);
        giz2 = pkfma(mk2(wz.x,wz.y), ur2[2*qd], giz2); giz2 = pkfma(mk2(wz.z,wz.w), ur2[2*qd+1], giz2);
        gin2 = pkfma(mk2(wn.x,wn.y), ur2[2*qd], gin2); gin2 = pkfma(mk2(wn.z,wn.w), ur2[2*qd+1], gin2);
        ghr2 = pkfma(mk2(vr.x,vr.y), hr2[2*qd], ghr2); ghr2 = pkfma(mk2(vr.z,vr.w), hr2[2*qd+1], ghr2);
        ghz2 = pkfma(mk2(vz.x,vz.y), hr2[2*qd], ghz2); ghz2 = pkfma(mk2(vz.z,vz.w), hr2[2*qd+1], ghz2);
        ghn2 = pkfma(mk2(vn.x,vn.y), hr2[2*qd], ghn2); ghn2 = pkfma(mk2(vn.z,vn.w), hr2[2*qd+1], ghn2);
      }
      float rg = sigm((gir2.x+gir2.y) + (ghr2.x+ghr2.y));
      float zg = sigm((giz2.x+giz2.y) + (ghz2.x+ghz2.y));
      float nh = fast_tanh((gin2.x+gin2.y) + rg*(ghn2.x+ghn2.y));
      s_reg = (1.f - zg)*nh + zg*s_reg;
    }

    // ---------- P5: block-cooperative decode via folded M2T ----------
    svb[wid*68 + lane] = s_reg;
    __syncthreads();
    {
      const int u = lane & 7, r = lane >> 3;
      const int pix = (wid << 5) | (u << 2);     // wave owns a 32-px column slice
      const float* m2p = g_M2T + pix;
      float4 c0 = *(const float4*)&C0L[pix];
      f32x2 a01 = mk2(c0.x, c0.y), a23 = mk2(c0.z, c0.w);
      #pragma unroll 4
      for (int q4 = 0; q4 < 16; ++q4) {
        float4 sv = *(const float4*)&svb[r*68 + 4*q4];
        f32x2 svA = mk2(sv.x, sv.y), svB = mk2(sv.z, sv.w);
        float4 m0 = *(const float4*)(m2p + (4*q4+0)*256);
        float4 m1 = *(const float4*)(m2p + (4*q4+1)*256);
        float4 m2 = *(const float4*)(m2p + (4*q4+2)*256);
        float4 m3 = *(const float4*)(m2p + (4*q4+3)*256);
        a01 = pkfma_blo(mk2(m0.x,m0.y), svA, a01); a23 = pkfma_blo(mk2(m0.z,m0.w), svA, a23);
        a01 = pkfma_bhi(mk2(m1.x,m1.y), svA, a01); a23 = pkfma_bhi(mk2(m1.z,m1.w), svA, a23);
        a01 = pkfma_blo(mk2(m2.x,m2.y), svB, a01); a23 = pkfma_blo(mk2(m2.z,m2.w), svB, a23);
        a01 = pkfma_bhi(mk2(m3.x,m3.y), svB, a01); a23 = pkfma_bhi(mk2(m3.z,m3.w), svB, a23);
      }
      const size_t ob = (size_t)(blockIdx.x*BPB + r)*(6*256) + (size_t)st*256 + pix;
      *(float4*)(out + ob) = make_float4(sigm(a01.x), sigm(a01.y), sigm(a23.x), sigm(a23.y));
    }
    __syncthreads();
  }
}

extern "C" void kernel_launch(void* const* d_in, const int* in_sizes, int n_in,
                              void* d_out, int out_size, void* d_ws, size_t ws_size,
                              hipStream_t stream) {
  const float* frames  = (const float*)d_in[0];
  const float* enc_w   = (const float*)d_in[1];
  const float* enc_b   = (const float*)d_in[2];
  const float* ln_w    = (const float*)d_in[3];
  const float* ln_b    = (const float*)d_in[4];
  const float* slot_mu = (const float*)d_in[5];
  const float* wq      = (const float*)d_in[6];
  const float* wk      = (const float*)d_in[7];
  const float* wv      = (const float*)d_in[8];
  const float* wih     = (const float*)d_in[9];
  const float* whh     = (const float*)d_in[10];
  const float* bih     = (const float*)d_in[11];
  const float* bhh     = (const float*)d_in[12];
  const float* s2s_w   = (const float*)d_in[13];
  const float* s2s_b   = (const float*)d_in[14];
  const float* mix_w   = (const float*)d_in[15];
  const float* mix_b   = (const float*)d_in[16];
  const float* dec_w   = (const float*)d_in[17];
  const float* dec_b   = (const float*)d_in[18];
  float* out = (float*)d_out;

  float* g_M2T = (float*)d_ws;            // 64*256 floats
  float* g_C0  = g_M2T + 64*256;          // 256 floats
  float* g_WKQ = g_C0 + 256;              // 256 floats (68,608 B total in d_ws)

  hipLaunchKernelGGL(prep_kernel, dim3(1), dim3(256), 0, stream,
                     s2s_w, s2s_b, mix_w, mix_b, dec_w, dec_b, wq, wk,
                     g_M2T, g_C0, g_WKQ);

  const int B = 16384;
  hipLaunchKernelGGL(microslot_kernel, dim3(B / BPB), dim3(TH), 0, stream,
                     frames, enc_w, enc_b, ln_w, ln_b, slot_mu, wv,
                     wih, whh, bih, bhh, g_M2T, g_C0, g_WKQ, out);
}